// Round 4
// baseline (113.446 us; speedup 1.0000x reference)
//
#include <hip/hip_runtime.h>
#include <hip/hip_bf16.h>
#include <math.h>

#define DD 48
#define NN 512
#define TWO_D 96
#define ROWS 2048   // B*N = 4*512

typedef __attribute__((ext_vector_type(8))) short bf16x8;
typedef __attribute__((ext_vector_type(4))) float f32x4;

// fast GELU: sigmoid form of the tanh approximation.
// h = u * sigmoid(1.59577*u + 0.0713548*u^3); max |err| vs exact-erf gelu ~5e-4 for |u|<3.
__device__ __forceinline__ float gelu_fast(float u) {
    const float u2 = u * u;
    const float yn = u * fmaf(u2, -0.10295347f, -2.3022587f);  // -(2z)*log2(e)
    const float e = __builtin_amdgcn_exp2f(yn);
    return u * __builtin_amdgcn_rcpf(1.0f + e);
}

// Kernel 1: blocks 0..511: A[r][t] = x_r @ W1[:48,t] + b1[t]; Bb[r][t] = x_r @ W1[48:,t]
//           block 512:     W2T[f][k] = bf16(W2[k][f])   (for direct B-fragment loads)
__global__ __launch_bounds__(256) void precompute_kernel(
        const float* __restrict__ x,
        const float* __restrict__ W1,
        const float* __restrict__ b1,
        const float* __restrict__ W2,
        float* __restrict__ Aout,
        float* __restrict__ Bout,
        __hip_bfloat16* __restrict__ W2T) {
    if (blockIdx.x == ROWS / 4) {
        for (int idx = threadIdx.x; idx < DD * TWO_D; idx += 256) {
            const int f = idx / TWO_D;
            const int k = idx - f * TWO_D;
            W2T[idx] = __float2bfloat16(W2[k * DD + f]);
        }
        return;
    }
    const int wave = threadIdx.x >> 6;
    const int lane = threadIdx.x & 63;
    const int row = blockIdx.x * 4 + wave;
    __shared__ float xs[4][DD];
    if (threadIdx.x < 4 * DD)
        xs[threadIdx.x / DD][threadIdx.x % DD] = x[blockIdx.x * 4 * DD + threadIdx.x];
    __syncthreads();
    for (int t = lane; t < TWO_D; t += 64) {
        float a0 = 0.f, a1 = 0.f;
#pragma unroll 8
        for (int k = 0; k < DD; ++k) {
            const float xv = xs[wave][k];
            a0 = fmaf(xv, W1[k * TWO_D + t], a0);
            a1 = fmaf(xv, W1[(DD + k) * TWO_D + t], a1);
        }
        Aout[row * TWO_D + t] = a0 + b1[t];
        Bout[row * TWO_D + t] = a1;
    }
}

// Kernel 2: one block per (b,i) row, heaviest rows first, 8 waves; wave w owns
// j-chunks w, w+8, ... Lane (n=lane&15, q=lane>>4) computes its MFMA A-fragment
// H[n][ks*32+q*8+0..7] = gelu(A_i + Bb_{j0+n}) in registers, 9 MFMA -> P[16][48],
// then FIXED-SHIFT softmax (norms are O(1), exp(w) cannot overflow): per-lane
// additive partials (l, o), merged once at the end across quads then waves.
__global__ __launch_bounds__(512) void pair_softmax_kernel(
        const float* __restrict__ Arow,
        const float* __restrict__ Brow,
        const __hip_bfloat16* __restrict__ W2T,
        const float* __restrict__ b2,
        float* __restrict__ out) {
    const int row = (ROWS - 1) - blockIdx.x;   // heavy (large i) rows dispatched first
    const int i = row & (NN - 1);
    const int tid = threadIdx.x;
    const int wave = tid >> 6;                 // 0..7
    const int lane = tid & 63;
    const int n = lane & 15;   // MFMA A-row / C col index
    const int q = lane >> 4;   // quad
    const int q8 = q * 8;

    // j rows live in the SAME batch: global j-row = (row - i) + j
    const float* __restrict__ Bbase = Brow + (size_t)(row - i) * TWO_D;

    // B fragments straight from global (L2-hit, once per block): B[k][f],
    // lane n = f (col), k = ks*32 + q*8 + 0..7
    bf16x8 bfrag[3][3];
#pragma unroll
    for (int t = 0; t < 3; ++t)
#pragma unroll
        for (int ks = 0; ks < 3; ++ks)
            bfrag[t][ks] = *(const bf16x8*)&W2T[(t * 16 + n) * TWO_D + ks * 32 + q8];
    float b2v[3];
#pragma unroll
    for (int t = 0; t < 3; ++t) b2v[t] = b2[t * 16 + n];

    // A_i values this lane needs: k = ks*32 + q*8 + 0..7  (register-resident)
    float av[3][8];
#pragma unroll
    for (int ks = 0; ks < 3; ++ks) {
        const float4 a0 = *(const float4*)&Arow[(size_t)row * TWO_D + ks * 32 + q8];
        const float4 a1 = *(const float4*)&Arow[(size_t)row * TWO_D + ks * 32 + q8 + 4];
        av[ks][0] = a0.x; av[ks][1] = a0.y; av[ks][2] = a0.z; av[ks][3] = a0.w;
        av[ks][4] = a1.x; av[ks][5] = a1.y; av[ks][6] = a1.z; av[ks][7] = a1.w;
    }

    float l_run = 0.f;
    float o_run[3] = {0.f, 0.f, 0.f};

    const int nchunks = (i + 16) >> 4;   // ceil((i+1)/16); j0+15 <= 511 always

    for (int c = wave; c < nchunks; c += 8) {
        const int j0 = c << 4;
        const float* __restrict__ Bj = Bbase + (size_t)(j0 + n) * TWO_D;

        // ---- Fused: A-frag in registers, 9 MFMA
        f32x4 acc[3] = {{0.f,0.f,0.f,0.f},{0.f,0.f,0.f,0.f},{0.f,0.f,0.f,0.f}};
#pragma unroll
        for (int ks = 0; ks < 3; ++ks) {
            const float4 bv0 = *(const float4*)&Bj[ks * 32 + q8];
            const float4 bv1 = *(const float4*)&Bj[ks * 32 + q8 + 4];
            float h[8];
            h[0] = gelu_fast(av[ks][0] + bv0.x);
            h[1] = gelu_fast(av[ks][1] + bv0.y);
            h[2] = gelu_fast(av[ks][2] + bv0.z);
            h[3] = gelu_fast(av[ks][3] + bv0.w);
            h[4] = gelu_fast(av[ks][4] + bv1.x);
            h[5] = gelu_fast(av[ks][5] + bv1.y);
            h[6] = gelu_fast(av[ks][6] + bv1.z);
            h[7] = gelu_fast(av[ks][7] + bv1.w);
            union { bf16x8 v; __hip_bfloat162 h2[4]; } af;
#pragma unroll
            for (int p = 0; p < 4; ++p)
                af.h2[p] = __float22bfloat162_rn(make_float2(h[2 * p], h[2 * p + 1]));
            acc[0] = __builtin_amdgcn_mfma_f32_16x16x32_bf16(af.v, bfrag[0][ks], acc[0], 0, 0, 0);
            acc[1] = __builtin_amdgcn_mfma_f32_16x16x32_bf16(af.v, bfrag[1][ks], acc[1], 0, 0, 0);
            acc[2] = __builtin_amdgcn_mfma_f32_16x16x32_bf16(af.v, bfrag[2][ks], acc[2], 0, 0, 0);
        }

        // ---- Epilogue: C/D layout row j_local = 4q+r, col f = t*16+n
        float pv[3][4];
        float ss[4];
#pragma unroll
        for (int r = 0; r < 4; ++r) {
            float s = 0.f;
#pragma unroll
            for (int t = 0; t < 3; ++t) {
                const float p = acc[t][r] + b2v[t];
                pv[t][r] = p;
                s = fmaf(p, p, s);
            }
            ss[r] = s;
        }
        // sum of squares over all 48 f: reduce across the 16 lanes of the quad
#pragma unroll
        for (int d = 1; d <= 8; d <<= 1) {
#pragma unroll
            for (int r = 0; r < 4; ++r) ss[r] += __shfl_xor(ss[r], d);
        }
        // fixed-shift softmax partials: ew = exp(||p||), masked -> 0
        float ew[4];
#pragma unroll
        for (int r = 0; r < 4; ++r) {
            const int j = j0 + 4 * q + r;
            ew[r] = (j <= i) ? __expf(sqrtf(ss[r])) : 0.f;
        }
        l_run += (ew[0] + ew[1]) + (ew[2] + ew[3]);
#pragma unroll
        for (int t = 0; t < 3; ++t)
            o_run[t] += ew[0]*pv[t][0] + ew[1]*pv[t][1] + ew[2]*pv[t][2] + ew[3]*pv[t][3];
    }

    // ---- Merge: sum across quads (shfl), then across 8 waves (LDS)
    l_run += __shfl_xor(l_run, 16);
    l_run += __shfl_xor(l_run, 32);
#pragma unroll
    for (int t = 0; t < 3; ++t) {
        o_run[t] += __shfl_xor(o_run[t], 16);
        o_run[t] += __shfl_xor(o_run[t], 32);
    }
    __shared__ float lred[8];
    __shared__ float ored[8][DD];
    if (lane < 16) {
#pragma unroll
        for (int t = 0; t < 3; ++t) ored[wave][t * 16 + n] = o_run[t];
    }
    if (lane == 0) lred[wave] = l_run;
    __syncthreads();
    if (tid < DD) {
        float L = 0.f, O = 0.f;
#pragma unroll
        for (int wv = 0; wv < 8; ++wv) {
            L += lred[wv];
            O += ored[wv][tid];
        }
        out[row * DD + tid] = O / L;
    }
}

extern "C" void kernel_launch(void* const* d_in, const int* in_sizes, int n_in,
                              void* d_out, int out_size, void* d_ws, size_t ws_size,
                              hipStream_t stream) {
    const float* x  = (const float*)d_in[0];
    const float* W1 = (const float*)d_in[1];
    const float* b1 = (const float*)d_in[2];
    const float* W2 = (const float*)d_in[3];
    const float* b2 = (const float*)d_in[4];
    float* outp = (float*)d_out;

    float* A  = (float*)d_ws;                           // 2048*96 fp32
    float* Bb = A + ROWS * TWO_D;                       // 2048*96 fp32
    __hip_bfloat16* W2T = (__hip_bfloat16*)(Bb + ROWS * TWO_D);  // 48*96 bf16

    precompute_kernel<<<ROWS / 4 + 1, 256, 0, stream>>>(x, W1, b1, W2, A, Bb, W2T);
    pair_softmax_kernel<<<ROWS, 512, 0, stream>>>(A, Bb, W2T, b2, outp);
}

// Round 5
// 104.452 us; speedup vs baseline: 1.0861x; 1.0861x over previous
//
#include <hip/hip_runtime.h>
#include <hip/hip_bf16.h>
#include <math.h>

#define DD 48
#define NN 512
#define TWO_D 96
#define ROWS 2048   // B*N = 4*512

typedef __attribute__((ext_vector_type(8))) short bf16x8;
typedef __attribute__((ext_vector_type(4))) float f32x4;

// fast GELU: sigmoid form of the tanh approximation.
// h = u * sigmoid(1.59577*u + 0.0713548*u^3); max |err| vs exact-erf gelu ~5e-4 for |u|<3.
__device__ __forceinline__ float gelu_fast(float u) {
    const float u2 = u * u;
    const float yn = u * fmaf(u2, -0.10295347f, -2.3022587f);  // -(2z)*log2(e)
    const float e = __builtin_amdgcn_exp2f(yn);
    return u * __builtin_amdgcn_rcpf(1.0f + e);
}

// Kernel 1: blocks 0..511: A[r][t] = x_r @ W1[:48,t] + b1[t]; Bb[r][t] = x_r @ W1[48:,t]
//           block 512:     W2T[f][k] = bf16(W2[k][f])   (for direct B-fragment loads)
__global__ __launch_bounds__(256) void precompute_kernel(
        const float* __restrict__ x,
        const float* __restrict__ W1,
        const float* __restrict__ b1,
        const float* __restrict__ W2,
        float* __restrict__ Aout,
        float* __restrict__ Bout,
        __hip_bfloat16* __restrict__ W2T) {
    if (blockIdx.x == ROWS / 4) {
        for (int idx = threadIdx.x; idx < DD * TWO_D; idx += 256) {
            const int f = idx / TWO_D;
            const int k = idx - f * TWO_D;
            W2T[idx] = __float2bfloat16(W2[k * DD + f]);
        }
        return;
    }
    const int wave = threadIdx.x >> 6;
    const int lane = threadIdx.x & 63;
    const int row = blockIdx.x * 4 + wave;
    __shared__ float xs[4][DD];
    if (threadIdx.x < 4 * DD)
        xs[threadIdx.x / DD][threadIdx.x % DD] = x[blockIdx.x * 4 * DD + threadIdx.x];
    __syncthreads();
    for (int t = lane; t < TWO_D; t += 64) {
        float a0 = 0.f, a1 = 0.f;
#pragma unroll 8
        for (int k = 0; k < DD; ++k) {
            const float xv = xs[wave][k];
            a0 = fmaf(xv, W1[k * TWO_D + t], a0);
            a1 = fmaf(xv, W1[(DD + k) * TWO_D + t], a1);
        }
        Aout[row * TWO_D + t] = a0 + b1[t];
        Bout[row * TWO_D + t] = a1;
    }
}

// Kernel 2: one block per (b,i) row; CU-BALANCED row mapping (see below); 4 waves,
// wave w owns j-chunks w, w+4, ... Lane (n, q) computes its MFMA A-fragment
// H[n][ks*32+q*8+0..7] = gelu(A_i + Bb_{j0+n}) in registers (next chunk's B-values
// prefetched during current compute), 9 MFMA -> P[16][48], fixed-shift softmax
// (norms are O(1), exp can't overflow), additive partials merged at the end.
__global__ __launch_bounds__(256) void pair_softmax_kernel(
        const float* __restrict__ Arow,
        const float* __restrict__ Brow,
        const __hip_bfloat16* __restrict__ W2T,
        const float* __restrict__ b2,
        float* __restrict__ out) {
    // Epoch-balanced mapping: blocks dispatch round-robin to 256 CUs; CU c gets one
    // block per 256-epoch. Epochs cover i-bands {448,0,384,64,320,128,256,192}+[0,63],
    // snaked on odd epochs, so every CU's 8 blocks have Sum(i) = 2044 = const.
    const int e = blockIdx.x >> 8;          // 0..7
    const int p = blockIdx.x & 255;
    const int base = (e & 1) ? ((e >> 1) << 6) : (448 - ((e >> 1) << 6));
    const int off = (e & 1) ? (63 - (p >> 2)) : (p >> 2);
    const int i = base + off;
    const int row = (p & 3) * NN + i;

    const int tid = threadIdx.x;
    const int wave = tid >> 6;                 // 0..3
    const int lane = tid & 63;
    const int n = lane & 15;   // MFMA A-row / C col index
    const int q = lane >> 4;   // quad
    const int q8 = q * 8;

    // j rows live in the SAME batch: global j-row = (row - i) + j
    const float* __restrict__ Bbase = Brow + (size_t)(row - i) * TWO_D;

    // B fragments straight from global (L2-hit, once per block): B[k][f],
    // lane n = f (col), k = ks*32 + q*8 + 0..7
    bf16x8 bfrag[3][3];
#pragma unroll
    for (int t = 0; t < 3; ++t)
#pragma unroll
        for (int ks = 0; ks < 3; ++ks)
            bfrag[t][ks] = *(const bf16x8*)&W2T[(t * 16 + n) * TWO_D + ks * 32 + q8];
    float b2v[3];
#pragma unroll
    for (int t = 0; t < 3; ++t) b2v[t] = b2[t * 16 + n];

    // A_i values this lane needs: k = ks*32 + q*8 + 0..7  (register-resident)
    float av[3][8];
#pragma unroll
    for (int ks = 0; ks < 3; ++ks) {
        const float4 a0 = *(const float4*)&Arow[(size_t)row * TWO_D + ks * 32 + q8];
        const float4 a1 = *(const float4*)&Arow[(size_t)row * TWO_D + ks * 32 + q8 + 4];
        av[ks][0] = a0.x; av[ks][1] = a0.y; av[ks][2] = a0.z; av[ks][3] = a0.w;
        av[ks][4] = a1.x; av[ks][5] = a1.y; av[ks][6] = a1.z; av[ks][7] = a1.w;
    }

    float l_run = 0.f;
    float o_run[3] = {0.f, 0.f, 0.f};

    const int nchunks = (i + 16) >> 4;   // ceil((i+1)/16); j0+15 <= 511 always
    const ptrdiff_t cstep = 64 * TWO_D;  // 4 chunks = 64 j-rows ahead

    // Software pipeline: pb holds the CURRENT chunk's 6 float4 B-values.
    const float* __restrict__ Bj = Bbase + (size_t)(wave * 16 + n) * TWO_D;
    float4 pb[6];
    if (wave < nchunks) {
#pragma unroll
        for (int ks = 0; ks < 3; ++ks) {
            pb[2 * ks]     = *(const float4*)&Bj[ks * 32 + q8];
            pb[2 * ks + 1] = *(const float4*)&Bj[ks * 32 + q8 + 4];
        }
    }

    for (int c = wave; c < nchunks; c += 4) {
        const int j0 = c << 4;
        const bool hn = (c + 4) < nchunks;     // wave-uniform
        const float* __restrict__ Bjn = Bj + cstep;

        f32x4 acc[3] = {{0.f,0.f,0.f,0.f},{0.f,0.f,0.f,0.f},{0.f,0.f,0.f,0.f}};
#pragma unroll
        for (int ks = 0; ks < 3; ++ks) {
            const float4 bv0 = pb[2 * ks];
            const float4 bv1 = pb[2 * ks + 1];
            if (hn) {   // issue next chunk's loads NOW; they land during compute
                pb[2 * ks]     = *(const float4*)&Bjn[ks * 32 + q8];
                pb[2 * ks + 1] = *(const float4*)&Bjn[ks * 32 + q8 + 4];
            }
            float h[8];
            h[0] = gelu_fast(av[ks][0] + bv0.x);
            h[1] = gelu_fast(av[ks][1] + bv0.y);
            h[2] = gelu_fast(av[ks][2] + bv0.z);
            h[3] = gelu_fast(av[ks][3] + bv0.w);
            h[4] = gelu_fast(av[ks][4] + bv1.x);
            h[5] = gelu_fast(av[ks][5] + bv1.y);
            h[6] = gelu_fast(av[ks][6] + bv1.z);
            h[7] = gelu_fast(av[ks][7] + bv1.w);
            union { bf16x8 v; __hip_bfloat162 h2[4]; } af;
#pragma unroll
            for (int pp = 0; pp < 4; ++pp)
                af.h2[pp] = __float22bfloat162_rn(make_float2(h[2 * pp], h[2 * pp + 1]));
            acc[0] = __builtin_amdgcn_mfma_f32_16x16x32_bf16(af.v, bfrag[0][ks], acc[0], 0, 0, 0);
            acc[1] = __builtin_amdgcn_mfma_f32_16x16x32_bf16(af.v, bfrag[1][ks], acc[1], 0, 0, 0);
            acc[2] = __builtin_amdgcn_mfma_f32_16x16x32_bf16(af.v, bfrag[2][ks], acc[2], 0, 0, 0);
        }
        Bj = Bjn;

        // ---- Epilogue: C/D layout row j_local = 4q+r, col f = t*16+n
        float pv[3][4];
        float ss[4];
#pragma unroll
        for (int r = 0; r < 4; ++r) {
            float s = 0.f;
#pragma unroll
            for (int t = 0; t < 3; ++t) {
                const float pz = acc[t][r] + b2v[t];
                pv[t][r] = pz;
                s = fmaf(pz, pz, s);
            }
            ss[r] = s;
        }
        // sum of squares over all 48 f: reduce across the 16 lanes of the quad
#pragma unroll
        for (int d = 1; d <= 8; d <<= 1) {
#pragma unroll
            for (int r = 0; r < 4; ++r) ss[r] += __shfl_xor(ss[r], d);
        }
        // fixed-shift softmax partials: ew = exp(||p||), masked -> 0
        float ew[4];
#pragma unroll
        for (int r = 0; r < 4; ++r) {
            const int j = j0 + 4 * q + r;
            ew[r] = (j <= i) ? __expf(sqrtf(ss[r])) : 0.f;
        }
        l_run += (ew[0] + ew[1]) + (ew[2] + ew[3]);
#pragma unroll
        for (int t = 0; t < 3; ++t)
            o_run[t] += ew[0]*pv[t][0] + ew[1]*pv[t][1] + ew[2]*pv[t][2] + ew[3]*pv[t][3];
    }

    // ---- Merge: sum across quads (shfl), then across 4 waves (LDS)
    l_run += __shfl_xor(l_run, 16);
    l_run += __shfl_xor(l_run, 32);
#pragma unroll
    for (int t = 0; t < 3; ++t) {
        o_run[t] += __shfl_xor(o_run[t], 16);
        o_run[t] += __shfl_xor(o_run[t], 32);
    }
    __shared__ float lred[4];
    __shared__ float ored[4][DD];
    if (lane < 16) {
#pragma unroll
        for (int t = 0; t < 3; ++t) ored[wave][t * 16 + n] = o_run[t];
    }
    if (lane == 0) lred[wave] = l_run;
    __syncthreads();
    if (tid < DD) {
        float L = 0.f, O = 0.f;
#pragma unroll
        for (int wv = 0; wv < 4; ++wv) {
            L += lred[wv];
            O += ored[wv][tid];
        }
        out[row * DD + tid] = O / L;
    }
}

extern "C" void kernel_launch(void* const* d_in, const int* in_sizes, int n_in,
                              void* d_out, int out_size, void* d_ws, size_t ws_size,
                              hipStream_t stream) {
    const float* x  = (const float*)d_in[0];
    const float* W1 = (const float*)d_in[1];
    const float* b1 = (const float*)d_in[2];
    const float* W2 = (const float*)d_in[3];
    const float* b2 = (const float*)d_in[4];
    float* outp = (float*)d_out;

    float* A  = (float*)d_ws;                           // 2048*96 fp32
    float* Bb = A + ROWS * TWO_D;                       // 2048*96 fp32
    __hip_bfloat16* W2T = (__hip_bfloat16*)(Bb + ROWS * TWO_D);  // 48*96 bf16

    precompute_kernel<<<ROWS / 4 + 1, 256, 0, stream>>>(x, W1, b1, W2, A, Bb, W2T);
    pair_softmax_kernel<<<ROWS, 256, 0, stream>>>(A, Bb, W2T, b2, outp);
}